// Round 6
// baseline (451.547 us; speedup 1.0000x reference)
//
#include <hip/hip_runtime.h>

#define BB 16
#define PP 131072
#define GG 64
#define THRESH 0.35f
#define RMAX 0.086f          // max prior half-extent 0.085 + slop margin
#define NCHUNK 16            // blocks per image
#define CPRIOR 8192          // priors per chunk

// ---------------- workspace layout (bytes) ----------------
// NOTHING needs host-side zeroing: partial arrays are written unconditionally;
// cidx/done are zeroed by k_loss (kernel-boundary visibility before consumers).
#define OFF_BESTP  0          // u64[BB][16][64]    131072
#define OFF_H1C    131072     // u32[BB][16][4096]  4194304
#define OFF_H1S    4325376    // f32[BB][16][4096]  4194304
#define OFF_NPOSP  8519680    // i32[BB][16]        1024
#define OFF_PCP    8520704    // f32[BB][16]        1024
#define OFF_LOCP   8521728    // f32[BB][16]        1024
#define OFF_CIDX   8522752    // u32[BB]            64
#define OFF_DONE   8522816    // u32                64
#define OFF_SELI   8522880    // i32[BB][4]         256  (sel1,kk1,np,k)
#define OFF_RESN   8523136    // i32[BB]
#define OFF_RESK   8523200    // i32[BB]
#define OFF_RESC   8523264    // f32[BB]
#define OFF_RESL   8523328    // f32[BB]
#define OFF_KEYS   8523392    // u32[BB*PP]  8388608
#define OFF_BTO    16912000   // f32[BB*PP]  8388608
#define OFF_BTI    25300608   // u8 [BB*PP]  2097152
#define OFF_CAND   27397760   // u32[BB*PP]  8388608   (total ~34.1 MB)

// ---------------- kernel 1: mask raster (LDS) + match ----------------
// grid (NCHUNK, BB) x 1024; 8 priors/thread strided by 1024.
__global__ __launch_bounds__(1024) void k_match(
    const float* __restrict__ priorbox, const float* __restrict__ targets,
    unsigned long long* __restrict__ bestp, float* __restrict__ bto,
    unsigned char* __restrict__ bti)
{
    __shared__ unsigned mlo[4096], mhi[4096];
    __shared__ float4 gxy[GG];
    __shared__ float gar[GG];
    __shared__ unsigned long long sbest[GG];
    const int b = blockIdx.y, chunk = blockIdx.x, tid = threadIdx.x;

    for (int i = tid; i < 4096; i += 1024) { mlo[i] = 0u; mhi[i] = 0u; }
    if (tid < GG) {
        const float* t = targets + (size_t)(b * GG + tid) * 5;
        float x1 = t[1], y1 = t[0], x2 = t[3], y2 = t[2];   // gts = t[[1,0,3,2]]
        gxy[tid] = make_float4(x1, y1, x2, y2);
        gar[tid] = (x2 - x1) * (y2 - y1);
        sbest[tid] = 0ull;
    }
    __syncthreads();

    // rasterize expanded gt boxes into the 64x64 cell bitmask
    {
        const int g = tid & 63, strip = tid >> 6;
        float4 a = gxy[g];
        float ex1 = a.x - RMAX, ey1 = a.y - RMAX;
        float ex2 = a.z + RMAX, ey2 = a.w + RMAX;
        int cx0 = max(0, (int)(ex1 * 64.f));
        int cx1 = min(63, (int)ceilf(ex2 * 64.f) - 1);
        int cy0 = max(0, (int)(ey1 * 64.f));
        int cy1 = min(63, (int)ceilf(ey2 * 64.f) - 1);
        unsigned bit = 1u << (g & 31);
        unsigned* marr = (g < 32) ? mlo : mhi;
        for (int cy = cy0 + strip; cy <= cy1; cy += 16)
            for (int cx = cx0; cx <= cx1; cx++)
                atomicOr(&marr[cy * 64 + cx], bit);
    }
    __syncthreads();

#pragma unroll
    for (int j = 0; j < 8; j++) {
        const int p = chunk * CPRIOR + j * 1024 + tid;
        float4 pr = *reinterpret_cast<const float4*>(priorbox + (size_t)p * 4);
        float hx = 0.5f * pr.z, hy = 0.5f * pr.w;
        float px1 = pr.x - hx, py1 = pr.y - hy;
        float px2 = pr.x + hx, py2 = pr.y + hy;
        float par = (px2 - px1) * (py2 - py1);
        int cx = min(63, max(0, (int)(pr.x * 64.f)));
        int cy = min(63, max(0, (int)(pr.y * 64.f)));
        const int cell = cy * 64 + cx;
        unsigned m0 = mlo[cell], m1 = mhi[cell];
        const unsigned long long notp = (unsigned long long)(~(unsigned)p);
        float bv = -1.f; int bg = 0;
#pragma unroll 1
        for (int half = 0; half < 2; half++) {
            unsigned m = half ? m1 : m0;
            const int gbase = half ? 32 : 0;
            while (m) {
                const int g = gbase + __ffs(m) - 1;       // ascending g: first-max tiebreak
                m &= m - 1;
                float4 a = gxy[g];
                float w = fminf(a.z, px2) - fmaxf(a.x, px1);
                float h = fminf(a.w, py2) - fmaxf(a.y, py1);
                w = fmaxf(w, 0.f); h = fmaxf(h, 0.f);
                float inter = w * h;
                float v = inter * __builtin_amdgcn_rcpf(gar[g] + par - inter);
                if (v > bv) { bv = v; bg = g; }
                if (v > 0.f) {
                    unsigned long long pk =
                        (((unsigned long long)__float_as_uint(v)) << 32) | notp;
                    atomicMax(&sbest[g], pk);
                }
            }
        }
        bto[(size_t)b * PP + p] = bv;
        bti[(size_t)b * PP + p] = (unsigned char)bg;
    }

    __syncthreads();
    if (tid < GG) bestp[(b * NCHUNK + chunk) * GG + tid] = sbest[tid];  // plain store
}

// ---------------- kernel 2: decode-in-LDS + loss + hist(counts+sums) ----------------
// grid (NCHUNK, BB) x 1024; 8 priors/thread strided by 1024.
__global__ __launch_bounds__(1024) void k_loss(
    const float* __restrict__ loc_preds, const float* __restrict__ cls_preds,
    const float* __restrict__ priorbox, const float* __restrict__ targets,
    const unsigned long long* __restrict__ bestp,
    const float* __restrict__ bto, const unsigned char* __restrict__ bti,
    unsigned* __restrict__ keys, unsigned* __restrict__ h1c, float* __restrict__ h1s,
    int* __restrict__ nposp, float* __restrict__ pcp, float* __restrict__ locp,
    unsigned* __restrict__ cidx, unsigned* __restrict__ done)
{
    __shared__ unsigned long long tmp64[1024];
    __shared__ unsigned hcnt[4096];
    __shared__ float hsum[4096];
    __shared__ float gx1[GG], gy1[GG], gx2[GG], gy2[GG], glab[GG];
    __shared__ unsigned blist[GG];
    __shared__ int nb;
    __shared__ float sred[32];
    __shared__ int sredi[16];
    const int b = blockIdx.y, chunk = blockIdx.x, tid = threadIdx.x;

    if (tid == 0 && chunk == 0) { cidx[b] = 0u; if (b == 0) *done = 0u; }

    tmp64[tid] = bestp[(b * NCHUNK + (tid >> 6)) * GG + (tid & 63)];
    for (int i = tid; i < 4096; i += 1024) { hcnt[i] = 0u; hsum[i] = 0.f; }
    if (tid < GG) {
        const float* t = targets + (size_t)(b * GG + tid) * 5;
        gx1[tid] = t[1]; gy1[tid] = t[0]; gx2[tid] = t[3]; gy2[tid] = t[2];
        glab[tid] = t[4];
    }
    __syncthreads();
    if (tid < GG) {
        unsigned long long m = tmp64[tid];
        for (int c = 1; c < NCHUNK; c++) {
            unsigned long long v = tmp64[c * GG + tid];
            m = v > m ? v : m;
        }
        tmp64[tid] = m;
    }
    __syncthreads();
    if (tid == 0) {
        int n = 0;
        for (int g = 0; g < GG; g++) {                    // ascending g: later-g wins at dup p
            unsigned long long m = tmp64[g];
            if (m) {
                unsigned p = ~((unsigned)(m & 0xFFFFFFFFull));
                if ((int)(p >> 13) == chunk) blist[n++] = ((p & 8191u) << 6) | (unsigned)g;
            }
        }
        nb = n;
    }
    __syncthreads();

    const int nbl = nb;
    float locpart = 0.f, clspart = 0.f; int cnt = 0;
#pragma unroll
    for (int j = 0; j < 8; j++) {
        const int plocal = j * 1024 + tid;
        const size_t ip = (size_t)b * PP + chunk * CPRIOR + plocal;
        const float bv = bto[ip];
        int g = bti[ip];
        bool isb = false;
        for (int i = 0; i < nbl; i++) {
            unsigned e = blist[i];
            if ((int)(e >> 6) == plocal) { isb = true; g = (int)(e & 63u); }
        }
        const float2 cl = *reinterpret_cast<const float2*>(cls_preds + ip * 2);
        const float mx = fmaxf(cl.x, cl.y);
        const float lse = mx + log1pf(expf(fminf(cl.x, cl.y) - mx));
        const float conf = isb ? glab[g] : ((bv < THRESH) ? 0.f : glab[g]);
        unsigned key = 0u;
        if (conf > 0.f) {
            float gathered = (((int)conf) == 0) ? cl.x : cl.y;
            clspart += lse - gathered;
            cnt++;
            const int p = chunk * CPRIOR + plocal;
            float4 pr = *reinterpret_cast<const float4*>(priorbox + (size_t)p * 4);
            float mx1 = gx1[g], my1 = gy1[g], mx2 = gx2[g], my2 = gy2[g];
            float gcx = ((mx1 + mx2) * 0.5f - pr.x) / (0.1f * pr.z);
            float gcy = ((my1 + my2) * 0.5f - pr.y) / (0.1f * pr.w);
            float gw = logf((mx2 - mx1) / pr.z) / 0.2f;
            float gh = logf((my2 - my1) / pr.w) / 0.2f;
            float4 lp = *reinterpret_cast<const float4*>(loc_preds + ip * 4);
            float d0 = lp.x - gcx, d1 = lp.y - gcy, d2 = lp.z - gw, d3 = lp.w - gh;
            float a0 = fabsf(d0), a1 = fabsf(d1), a2 = fabsf(d2), a3 = fabsf(d3);
            locpart += ((a0 < 1.f) ? 0.5f * d0 * d0 : a0 - 0.5f)
                     + ((a1 < 1.f) ? 0.5f * d1 * d1 : a1 - 0.5f)
                     + ((a2 < 1.f) ? 0.5f * d2 * d2 : a2 - 0.5f)
                     + ((a3 < 1.f) ? 0.5f * d3 * d3 : a3 - 0.5f);
        } else {
            float lc = lse - cl.x;                         // > 0 strictly for negs
            key = __float_as_uint(lc);
            atomicAdd(&hcnt[key >> 20], 1u);
            atomicAdd(&hsum[key >> 20], lc);
        }
        keys[ip] = key;
    }

    for (int o = 32; o; o >>= 1) {
        locpart += __shfl_xor(locpart, o);
        clspart += __shfl_xor(clspart, o);
        cnt     += __shfl_xor(cnt, o);
    }
    const int w = tid >> 6;
    if ((tid & 63) == 0) { sred[w] = locpart; sred[16 + w] = clspart; sredi[w] = cnt; }
    __syncthreads();
    if (tid == 0) {
        float l = 0.f, c = 0.f; int n = 0;
        for (int i = 0; i < 16; i++) { l += sred[i]; c += sred[16 + i]; n += sredi[i]; }
        nposp[b * NCHUNK + chunk] = n;                    // unconditional stores: no zeroing
        pcp[b * NCHUNK + chunk] = c;
        locp[b * NCHUNK + chunk] = l;
    }
    __syncthreads();
    for (int i = tid; i < 4096; i += 1024) {
        h1c[(b * NCHUNK + chunk) * 4096 + i] = hcnt[i];
        h1s[(b * NCHUNK + chunk) * 4096 + i] = hsum[i];
    }
}

// ---------------- parallel descending k-th finder (1024-thread block) ----------------
template <int NBINS>
__device__ void find_kth_par(const unsigned* __restrict__ h, int k, int* sel, int* krem)
{
    constexpr int PER = NBINS / 1024;
    __shared__ unsigned wsum_[16];
    __shared__ int res_[2];
    const int tid = threadIdx.x, lane = tid & 63, wid = tid >> 6;
    __syncthreads();
    unsigned own[PER];
    unsigned s = 0;
#pragma unroll
    for (int i = 0; i < PER; i++) { own[i] = h[NBINS - 1 - (tid * PER + i)]; s += own[i]; }
    unsigned incl = s;
    for (int d = 1; d < 64; d <<= 1) {
        unsigned t = __shfl_up(incl, d);
        if (lane >= d) incl += t;
    }
    if (lane == 63) wsum_[wid] = incl;
    if (tid == 0) { res_[0] = -1; res_[1] = 0; }
    __syncthreads();
    unsigned woff = 0;
    for (int w = 0; w < 16; w++) woff += (w < wid) ? wsum_[w] : 0u;
    const unsigned texcl = woff + incl - s;
    if (k > 0 && texcl < (unsigned)k && texcl + s >= (unsigned)k) {
        unsigned run = texcl;
#pragma unroll
        for (int i = 0; i < PER; i++) {
            run += own[i];
            if (run >= (unsigned)k) {
                res_[0] = NBINS - 1 - (tid * PER + i);
                res_[1] = k - (int)(run - own[i]);
                break;
            }
        }
    }
    __syncthreads();
    *sel = res_[0]; *krem = res_[1];
}

__device__ float block_sum_f(float v)
{
    __shared__ float rs[16];
    const int tid = threadIdx.x;
    __syncthreads();
    for (int o = 32; o; o >>= 1) v += __shfl_xor(v, o);
    if ((tid & 63) == 0) rs[tid >> 6] = v;
    __syncthreads();
    float s = 0.f;
    for (int i = 0; i < 16; i++) s += rs[i];
    return s;
}

// ---------------- kernel 3: find sel1 + compact bucket-sel1 keys ----------------
// grid (NCHUNK, BB) x 1024, 8 keys/thread
__global__ __launch_bounds__(1024) void k_compact(
    const unsigned* __restrict__ keys, const unsigned* __restrict__ h1c,
    const int* __restrict__ nposp, unsigned* __restrict__ cand,
    unsigned* __restrict__ cidx, int* __restrict__ seli)
{
    __shared__ unsigned h1tot[4096];
    __shared__ int snp;
    const int b = blockIdx.y, chunk = blockIdx.x, tid = threadIdx.x;
    if (tid == 0) {
        int np = 0;
        for (int c = 0; c < NCHUNK; c++) np += nposp[b * NCHUNK + c];
        snp = np;
    }
    for (int i = tid; i < 4096; i += 1024) {
        unsigned s = 0;
        for (int c = 0; c < NCHUNK; c++) s += h1c[(b * NCHUNK + c) * 4096 + i];
        h1tot[i] = s;
    }
    __syncthreads();
    const int np = snp;
    const int k = min(3 * np, PP - 1);
    int sel1, kk1;
    find_kth_par<4096>(h1tot, k, &sel1, &kk1);
    if (chunk == 0 && tid == 0) {
        seli[b * 4 + 0] = sel1; seli[b * 4 + 1] = kk1;
        seli[b * 4 + 2] = np;   seli[b * 4 + 3] = k;
    }
    const unsigned s1 = (unsigned)sel1;                   // -1 matches nothing
    const int lane = tid & 63;
#pragma unroll
    for (int j = 0; j < 8; j++) {
        const unsigned key = keys[(size_t)b * PP + chunk * CPRIOR + j * 1024 + tid];
        const bool pred = (key >> 20) == s1;
        unsigned long long mv = __ballot(pred);
        if (mv) {
            const int leader = __ffsll(mv) - 1;
            unsigned base = 0;
            if (lane == leader) base = atomicAdd(&cidx[b], (unsigned)__popcll(mv));
            base = __shfl(base, leader);
            if (pred) {
                unsigned long long lower = mv & ((1ull << lane) - 1ull);
                cand[(size_t)b * PP + base + __popcll(lower)] = key;
            }
        }
    }
}

// ---------------- kernel 4: exact top-k among candidates + per-image + final ----------------
// grid BB x 1024; last-done block computes the 3 outputs.
__global__ __launch_bounds__(1024) void k_select(
    const unsigned* __restrict__ cand, const unsigned* __restrict__ cidx,
    const float* __restrict__ h1s, const int* __restrict__ seli,
    const float* __restrict__ pcp, const float* __restrict__ locp,
    int* __restrict__ resn, int* __restrict__ resk,
    float* __restrict__ resc, float* __restrict__ resl,
    unsigned* __restrict__ done, float* __restrict__ out)
{
    __shared__ unsigned ch[1024];
    __shared__ float cs[1024];
    __shared__ float sbc[4];
    __shared__ int lastflag;
    const int b = blockIdx.x, tid = threadIdx.x;
    const int sel1 = seli[b * 4 + 0], kk1 = seli[b * 4 + 1];
    const int np   = seli[b * 4 + 2], k   = seli[b * 4 + 3];
    const unsigned ncand = cidx[b];

    // neg-sum over buckets strictly above sel1, from per-chunk bin sums
    float nh = 0.f;
    for (int i = tid * 4; i < tid * 4 + 4; i++) {
        if (i > sel1) {
            for (int c = 0; c < NCHUNK; c++) nh += h1s[(b * NCHUNK + c) * 4096 + i];
        }
    }
    float negsum_high = block_sum_f(nh);

    // pass 1: hist on bits [19:10] of candidates
    ch[tid] = 0u; cs[tid] = 0.f;
    __syncthreads();
    for (unsigned i = tid; i < ncand; i += 1024) {
        unsigned v = cand[(size_t)b * PP + i];
        unsigned bin = (v >> 10) & 1023u;
        atomicAdd(&ch[bin], 1u);
        atomicAdd(&cs[bin], __uint_as_float(v));
    }
    __syncthreads();
    int sel2, kk2;
    find_kth_par<1024>(ch, (sel1 < 0) ? 0 : kk1, &sel2, &kk2);
    float sumhi2 = block_sum_f((sel2 >= 0 && tid > sel2) ? cs[tid] : 0.f);

    // pass 2: hist on bits [9:0] within sub-bucket sel2
    __syncthreads();
    ch[tid] = 0u; cs[tid] = 0.f;
    __syncthreads();
    if (sel2 >= 0) {
        for (unsigned i = tid; i < ncand; i += 1024) {
            unsigned v = cand[(size_t)b * PP + i];
            if (((v >> 10) & 1023u) == (unsigned)sel2) {
                atomicAdd(&ch[v & 1023u], 1u);
                atomicAdd(&cs[v & 1023u], __uint_as_float(v));
            }
        }
    }
    __syncthreads();
    int sel3, needeq;
    find_kth_par<1024>(ch, (sel2 < 0) ? 0 : kk2, &sel3, &needeq);
    float sumhi3 = block_sum_f((sel3 >= 0 && tid > sel3) ? cs[tid] : 0.f);

    if (tid == 0) {
        float pcsum = 0.f, locsum = 0.f;
        for (int c = 0; c < NCHUNK; c++) {
            pcsum += pcp[b * NCHUNK + c];
            locsum += locp[b * NCHUNK + c];
        }
        float add = 0.f;
        if (sel3 >= 0 && needeq > 0) {
            unsigned Kstar = ((unsigned)sel1 << 20) | ((unsigned)sel2 << 10) | (unsigned)sel3;
            add = needeq * __uint_as_float(Kstar);
        }
        resn[b] = np;
        resk[b] = k;
        resc[b] = pcsum + negsum_high + sumhi2 + sumhi3 + add;
        resl[b] = locsum;
        __threadfence();
        unsigned old = atomicAdd(done, 1u);
        lastflag = (old == BB - 1) ? 1 : 0;
    }
    __syncthreads();
    if (!lastflag || tid != 0) return;

    __threadfence();
    volatile int* vrn = (volatile int*)resn;
    volatile int* vrk = (volatile int*)resk;
    volatile float* vrc = (volatile float*)resc;
    volatile float* vrl = (volatile float*)resl;
    int npt = 0; long long maskc = 0; float clsnum = 0.f, locnum = 0.f;
    for (int b2 = 0; b2 < BB; b2++) {
        npt += vrn[b2];
        maskc += (long long)vrn[b2] + vrk[b2];
        clsnum += vrc[b2];
        locnum += vrl[b2];
    }
    float denom_loc = (float)((4 * npt > 1) ? 4 * npt : 1);
    float denom_cls = (float)((maskc > 1) ? maskc : 1);
    float loss_loc = locnum / denom_loc;
    float loss_cls = clsnum / denom_cls;
    out[0] = (loss_cls + loss_loc) / (float)npt;
    out[1] = loss_loc;
    out[2] = loss_cls;
    (void)sbc;
}

extern "C" void kernel_launch(void* const* d_in, const int* in_sizes, int n_in,
                              void* d_out, int out_size, void* d_ws, size_t ws_size,
                              hipStream_t stream)
{
    const float* loc_preds = (const float*)d_in[0];
    const float* cls_preds = (const float*)d_in[1];
    const float* priorbox  = (const float*)d_in[2];
    const float* targets   = (const float*)d_in[3];
    float* out = (float*)d_out;

    char* ws = (char*)d_ws;
    unsigned long long* bestp = (unsigned long long*)(ws + OFF_BESTP);
    unsigned* h1c    = (unsigned*)(ws + OFF_H1C);
    float*    h1s    = (float*)(ws + OFF_H1S);
    int*      nposp  = (int*)(ws + OFF_NPOSP);
    float*    pcp    = (float*)(ws + OFF_PCP);
    float*    locp   = (float*)(ws + OFF_LOCP);
    unsigned* cidx   = (unsigned*)(ws + OFF_CIDX);
    unsigned* done   = (unsigned*)(ws + OFF_DONE);
    int*      seli   = (int*)(ws + OFF_SELI);
    int*      resn   = (int*)(ws + OFF_RESN);
    int*      resk   = (int*)(ws + OFF_RESK);
    float*    resc   = (float*)(ws + OFF_RESC);
    float*    resl   = (float*)(ws + OFF_RESL);
    unsigned* keys   = (unsigned*)(ws + OFF_KEYS);
    float*    bto    = (float*)(ws + OFF_BTO);
    unsigned char* bti = (unsigned char*)(ws + OFF_BTI);
    unsigned* cand   = (unsigned*)(ws + OFF_CAND);

    k_match<<<dim3(NCHUNK, BB), 1024, 0, stream>>>(priorbox, targets, bestp, bto, bti);
    k_loss<<<dim3(NCHUNK, BB), 1024, 0, stream>>>(loc_preds, cls_preds, priorbox, targets,
                                                  bestp, bto, bti, keys, h1c, h1s,
                                                  nposp, pcp, locp, cidx, done);
    k_compact<<<dim3(NCHUNK, BB), 1024, 0, stream>>>(keys, h1c, nposp, cand, cidx, seli);
    k_select<<<BB, 1024, 0, stream>>>(cand, cidx, h1s, seli, pcp, locp,
                                      resn, resk, resc, resl, done, out);
}

// Round 7
// 113.250 us; speedup vs baseline: 3.9872x; 3.9872x over previous
//
#include <hip/hip_runtime.h>

#define BB 16
#define PP 131072
#define GG 64
#define THRESH 0.35f
#define RMAX 0.086f          // max prior half-extent 0.085 + slop margin
#define NCHUNK 16            // blocks per image
#define CPRIOR 8192          // priors per chunk

// ---------------- workspace layout (bytes) ----------------
// NOTHING needs host-side zeroing: partial arrays are written unconditionally;
// cidx/done are zeroed by k_loss (kernel-boundary visibility before consumers).
#define OFF_BESTP  0          // u64[BB][16][64]    131072
#define OFF_H1C    131072     // u32[BB][16][4096]  4194304
#define OFF_H1S    4325376    // f32[BB][16][4096]  4194304
#define OFF_NPOSP  8519680    // i32[BB][16]        1024
#define OFF_PCP    8520704    // f32[BB][16]        1024
#define OFF_LOCP   8521728    // f32[BB][16]        1024
#define OFF_CIDX   8522752    // u32[BB]            64
#define OFF_DONE   8522816    // u32                64
#define OFF_SELI   8522880    // i32[BB][4]         256  (sel1,kk1,np,k)
#define OFF_RESN   8523136    // i32[BB]
#define OFF_RESK   8523200    // i32[BB]
#define OFF_RESC   8523264    // f32[BB]
#define OFF_RESL   8523328    // f32[BB]
#define OFF_KEYS   8523392    // u32[BB*PP]  8388608
#define OFF_BTO    16912000   // f32[BB*PP]  8388608
#define OFF_BTI    25300608   // u8 [BB*PP]  2097152
#define OFF_CAND   27397760   // u32[BB*PP]  8388608   (total ~34.1 MB)

// ---------------- kernel 1: mask raster (LDS) + match ----------------
// grid (NCHUNK, BB) x 1024; 8 priors/thread strided by 1024.
__global__ __launch_bounds__(1024) void k_match(
    const float* __restrict__ priorbox, const float* __restrict__ targets,
    unsigned long long* __restrict__ bestp, float* __restrict__ bto,
    unsigned char* __restrict__ bti)
{
    __shared__ unsigned mlo[4096], mhi[4096];
    __shared__ float4 gxy[GG];
    __shared__ float gar[GG];
    __shared__ unsigned long long sbest[GG];
    const int b = blockIdx.y, chunk = blockIdx.x, tid = threadIdx.x;

    for (int i = tid; i < 4096; i += 1024) { mlo[i] = 0u; mhi[i] = 0u; }
    if (tid < GG) {
        const float* t = targets + (size_t)(b * GG + tid) * 5;
        float x1 = t[1], y1 = t[0], x2 = t[3], y2 = t[2];   // gts = t[[1,0,3,2]]
        gxy[tid] = make_float4(x1, y1, x2, y2);
        gar[tid] = (x2 - x1) * (y2 - y1);
        sbest[tid] = 0ull;
    }
    __syncthreads();

    // rasterize expanded gt boxes into the 64x64 cell bitmask
    {
        const int g = tid & 63, strip = tid >> 6;
        float4 a = gxy[g];
        float ex1 = a.x - RMAX, ey1 = a.y - RMAX;
        float ex2 = a.z + RMAX, ey2 = a.w + RMAX;
        int cx0 = max(0, (int)(ex1 * 64.f));
        int cx1 = min(63, (int)ceilf(ex2 * 64.f) - 1);
        int cy0 = max(0, (int)(ey1 * 64.f));
        int cy1 = min(63, (int)ceilf(ey2 * 64.f) - 1);
        unsigned bit = 1u << (g & 31);
        unsigned* marr = (g < 32) ? mlo : mhi;
        for (int cy = cy0 + strip; cy <= cy1; cy += 16)
            for (int cx = cx0; cx <= cx1; cx++)
                atomicOr(&marr[cy * 64 + cx], bit);
    }
    __syncthreads();

#pragma unroll
    for (int j = 0; j < 8; j++) {
        const int p = chunk * CPRIOR + j * 1024 + tid;
        float4 pr = *reinterpret_cast<const float4*>(priorbox + (size_t)p * 4);
        float hx = 0.5f * pr.z, hy = 0.5f * pr.w;
        float px1 = pr.x - hx, py1 = pr.y - hy;
        float px2 = pr.x + hx, py2 = pr.y + hy;
        float par = (px2 - px1) * (py2 - py1);
        int cx = min(63, max(0, (int)(pr.x * 64.f)));
        int cy = min(63, max(0, (int)(pr.y * 64.f)));
        const int cell = cy * 64 + cx;
        unsigned m0 = mlo[cell], m1 = mhi[cell];
        const unsigned long long notp = (unsigned long long)(~(unsigned)p);
        float bv = -1.f; int bg = 0;
#pragma unroll 1
        for (int half = 0; half < 2; half++) {
            unsigned m = half ? m1 : m0;
            const int gbase = half ? 32 : 0;
            while (m) {
                const int g = gbase + __ffs(m) - 1;       // ascending g: first-max tiebreak
                m &= m - 1;
                float4 a = gxy[g];
                float w = fminf(a.z, px2) - fmaxf(a.x, px1);
                float h = fminf(a.w, py2) - fmaxf(a.y, py1);
                w = fmaxf(w, 0.f); h = fmaxf(h, 0.f);
                float inter = w * h;
                float v = inter * __builtin_amdgcn_rcpf(gar[g] + par - inter);
                if (v > bv) { bv = v; bg = g; }
                if (v > 0.f) {
                    unsigned long long pk =
                        (((unsigned long long)__float_as_uint(v)) << 32) | notp;
                    atomicMax(&sbest[g], pk);
                }
            }
        }
        bto[(size_t)b * PP + p] = bv;
        bti[(size_t)b * PP + p] = (unsigned char)bg;
    }

    __syncthreads();
    if (tid < GG) bestp[(b * NCHUNK + chunk) * GG + tid] = sbest[tid];  // plain store
}

// ---------------- kernel 2: decode-in-LDS + loss + hist(counts+sums) ----------------
// grid (NCHUNK, BB) x 1024; 8 priors/thread strided by 1024.
__global__ __launch_bounds__(1024) void k_loss(
    const float* __restrict__ loc_preds, const float* __restrict__ cls_preds,
    const float* __restrict__ priorbox, const float* __restrict__ targets,
    const unsigned long long* __restrict__ bestp,
    const float* __restrict__ bto, const unsigned char* __restrict__ bti,
    unsigned* __restrict__ keys, unsigned* __restrict__ h1c, float* __restrict__ h1s,
    int* __restrict__ nposp, float* __restrict__ pcp, float* __restrict__ locp,
    unsigned* __restrict__ cidx, unsigned* __restrict__ done)
{
    __shared__ unsigned long long tmp64[1024];
    __shared__ unsigned hcnt[4096];
    __shared__ float hsum[4096];
    __shared__ float gx1[GG], gy1[GG], gx2[GG], gy2[GG], glab[GG];
    __shared__ unsigned blist[GG];
    __shared__ int nb;
    __shared__ float sred[32];
    __shared__ int sredi[16];
    const int b = blockIdx.y, chunk = blockIdx.x, tid = threadIdx.x;

    if (tid == 0 && chunk == 0) { cidx[b] = 0u; if (b == 0) *done = 0u; }

    tmp64[tid] = bestp[(b * NCHUNK + (tid >> 6)) * GG + (tid & 63)];
    for (int i = tid; i < 4096; i += 1024) { hcnt[i] = 0u; hsum[i] = 0.f; }
    if (tid < GG) {
        const float* t = targets + (size_t)(b * GG + tid) * 5;
        gx1[tid] = t[1]; gy1[tid] = t[0]; gx2[tid] = t[3]; gy2[tid] = t[2];
        glab[tid] = t[4];
    }
    __syncthreads();
    if (tid < GG) {
        unsigned long long m = tmp64[tid];
        for (int c = 1; c < NCHUNK; c++) {
            unsigned long long v = tmp64[c * GG + tid];
            m = v > m ? v : m;
        }
        tmp64[tid] = m;
    }
    __syncthreads();
    if (tid == 0) {
        int n = 0;
        for (int g = 0; g < GG; g++) {                    // ascending g: later-g wins at dup p
            unsigned long long m = tmp64[g];
            if (m) {
                unsigned p = ~((unsigned)(m & 0xFFFFFFFFull));
                if ((int)(p >> 13) == chunk) blist[n++] = ((p & 8191u) << 6) | (unsigned)g;
            }
        }
        nb = n;
    }
    __syncthreads();

    const int nbl = nb;
    float locpart = 0.f, clspart = 0.f; int cnt = 0;
#pragma unroll
    for (int j = 0; j < 8; j++) {
        const int plocal = j * 1024 + tid;
        const size_t ip = (size_t)b * PP + chunk * CPRIOR + plocal;
        const float bv = bto[ip];
        int g = bti[ip];
        bool isb = false;
        for (int i = 0; i < nbl; i++) {
            unsigned e = blist[i];
            if ((int)(e >> 6) == plocal) { isb = true; g = (int)(e & 63u); }
        }
        const float2 cl = *reinterpret_cast<const float2*>(cls_preds + ip * 2);
        const float mx = fmaxf(cl.x, cl.y);
        const float lse = mx + log1pf(expf(fminf(cl.x, cl.y) - mx));
        const float conf = isb ? glab[g] : ((bv < THRESH) ? 0.f : glab[g]);
        unsigned key = 0u;
        if (conf > 0.f) {
            float gathered = (((int)conf) == 0) ? cl.x : cl.y;
            clspart += lse - gathered;
            cnt++;
            const int p = chunk * CPRIOR + plocal;
            float4 pr = *reinterpret_cast<const float4*>(priorbox + (size_t)p * 4);
            float mx1 = gx1[g], my1 = gy1[g], mx2 = gx2[g], my2 = gy2[g];
            float gcx = ((mx1 + mx2) * 0.5f - pr.x) / (0.1f * pr.z);
            float gcy = ((my1 + my2) * 0.5f - pr.y) / (0.1f * pr.w);
            float gw = logf((mx2 - mx1) / pr.z) / 0.2f;
            float gh = logf((my2 - my1) / pr.w) / 0.2f;
            float4 lp = *reinterpret_cast<const float4*>(loc_preds + ip * 4);
            float d0 = lp.x - gcx, d1 = lp.y - gcy, d2 = lp.z - gw, d3 = lp.w - gh;
            float a0 = fabsf(d0), a1 = fabsf(d1), a2 = fabsf(d2), a3 = fabsf(d3);
            locpart += ((a0 < 1.f) ? 0.5f * d0 * d0 : a0 - 0.5f)
                     + ((a1 < 1.f) ? 0.5f * d1 * d1 : a1 - 0.5f)
                     + ((a2 < 1.f) ? 0.5f * d2 * d2 : a2 - 0.5f)
                     + ((a3 < 1.f) ? 0.5f * d3 * d3 : a3 - 0.5f);
        } else {
            float lc = lse - cl.x;                         // > 0 strictly for negs
            key = __float_as_uint(lc);
            atomicAdd(&hcnt[key >> 20], 1u);
            atomicAdd(&hsum[key >> 20], lc);
        }
        keys[ip] = key;
    }

    for (int o = 32; o; o >>= 1) {
        locpart += __shfl_xor(locpart, o);
        clspart += __shfl_xor(clspart, o);
        cnt     += __shfl_xor(cnt, o);
    }
    const int w = tid >> 6;
    if ((tid & 63) == 0) { sred[w] = locpart; sred[16 + w] = clspart; sredi[w] = cnt; }
    __syncthreads();
    if (tid == 0) {
        float l = 0.f, c = 0.f; int n = 0;
        for (int i = 0; i < 16; i++) { l += sred[i]; c += sred[16 + i]; n += sredi[i]; }
        nposp[b * NCHUNK + chunk] = n;                    // unconditional stores: no zeroing
        pcp[b * NCHUNK + chunk] = c;
        locp[b * NCHUNK + chunk] = l;
    }
    __syncthreads();
    for (int i = tid; i < 4096; i += 1024) {
        h1c[(b * NCHUNK + chunk) * 4096 + i] = hcnt[i];
        h1s[(b * NCHUNK + chunk) * 4096 + i] = hsum[i];
    }
}

// ---------------- parallel descending k-th finder (1024-thread block) ----------------
template <int NBINS>
__device__ void find_kth_par(const unsigned* __restrict__ h, int k, int* sel, int* krem)
{
    constexpr int PER = NBINS / 1024;
    __shared__ unsigned wsum_[16];
    __shared__ int res_[2];
    const int tid = threadIdx.x, lane = tid & 63, wid = tid >> 6;
    __syncthreads();
    unsigned own[PER];
    unsigned s = 0;
#pragma unroll
    for (int i = 0; i < PER; i++) { own[i] = h[NBINS - 1 - (tid * PER + i)]; s += own[i]; }
    unsigned incl = s;
    for (int d = 1; d < 64; d <<= 1) {
        unsigned t = __shfl_up(incl, d);
        if (lane >= d) incl += t;
    }
    if (lane == 63) wsum_[wid] = incl;
    if (tid == 0) { res_[0] = -1; res_[1] = 0; }
    __syncthreads();
    unsigned woff = 0;
    for (int w = 0; w < 16; w++) woff += (w < wid) ? wsum_[w] : 0u;
    const unsigned texcl = woff + incl - s;
    if (k > 0 && texcl < (unsigned)k && texcl + s >= (unsigned)k) {
        unsigned run = texcl;
#pragma unroll
        for (int i = 0; i < PER; i++) {
            run += own[i];
            if (run >= (unsigned)k) {
                res_[0] = NBINS - 1 - (tid * PER + i);
                res_[1] = k - (int)(run - own[i]);
                break;
            }
        }
    }
    __syncthreads();
    *sel = res_[0]; *krem = res_[1];
}

__device__ float block_sum_f(float v)
{
    __shared__ float rs[16];
    const int tid = threadIdx.x;
    __syncthreads();
    for (int o = 32; o; o >>= 1) v += __shfl_xor(v, o);
    if ((tid & 63) == 0) rs[tid >> 6] = v;
    __syncthreads();
    float s = 0.f;
    for (int i = 0; i < 16; i++) s += rs[i];
    return s;
}

// ---------------- kernel 3: find sel1 + compact bucket-sel1 keys ----------------
// grid (NCHUNK, BB) x 1024, 8 keys/thread. ONE returning global atomic per
// BLOCK (R6's per-wave returning atomicAdd on cidx serialized: 347 us at
// 0.9% VALU — thousands of same-address round-trips).
__global__ __launch_bounds__(1024) void k_compact(
    const unsigned* __restrict__ keys, const unsigned* __restrict__ h1c,
    const int* __restrict__ nposp, unsigned* __restrict__ cand,
    unsigned* __restrict__ cidx, int* __restrict__ seli)
{
    __shared__ unsigned h1tot[4096];
    __shared__ int snp;
    __shared__ unsigned wcnt[16], wbase[16];
    __shared__ unsigned bbase;
    const int b = blockIdx.y, chunk = blockIdx.x, tid = threadIdx.x;
    const int lane = tid & 63, wid = tid >> 6;
    if (tid == 0) {
        int np = 0;
        for (int c = 0; c < NCHUNK; c++) np += nposp[b * NCHUNK + c];
        snp = np;
    }
    for (int i = tid; i < 4096; i += 1024) {
        unsigned s = 0;
        for (int c = 0; c < NCHUNK; c++) s += h1c[(b * NCHUNK + c) * 4096 + i];
        h1tot[i] = s;
    }
    // keys loaded once into registers; reused for ballot count + scatter
    unsigned kv[8];
#pragma unroll
    for (int j = 0; j < 8; j++)
        kv[j] = keys[(size_t)b * PP + chunk * CPRIOR + j * 1024 + tid];
    __syncthreads();
    const int np = snp;
    const int k = min(3 * np, PP - 1);
    int sel1, kk1;
    find_kth_par<4096>(h1tot, k, &sel1, &kk1);
    if (chunk == 0 && tid == 0) {
        seli[b * 4 + 0] = sel1; seli[b * 4 + 1] = kk1;
        seli[b * 4 + 2] = np;   seli[b * 4 + 3] = k;
    }
    const unsigned s1 = (unsigned)sel1;                   // -1 matches nothing

    // phase A: ballot masks + per-wave counts
    unsigned long long mv[8];
    unsigned wn = 0;
#pragma unroll
    for (int j = 0; j < 8; j++) {
        mv[j] = __ballot((kv[j] >> 20) == s1);
        wn += (unsigned)__popcll(mv[j]);
    }
    if (lane == 0) wcnt[wid] = wn;
    __syncthreads();
    if (tid == 0) {
        unsigned run = 0;
        for (int w = 0; w < 16; w++) { wbase[w] = run; run += wcnt[w]; }
        bbase = run ? atomicAdd(&cidx[b], run) : 0u;      // 1 returning atomic / block
    }
    __syncthreads();
    // phase B: scatter from registers with wave-uniform running offsets
    unsigned run = bbase + wbase[wid];
    const unsigned long long lanemask = (1ull << lane) - 1ull;
#pragma unroll
    for (int j = 0; j < 8; j++) {
        if ((kv[j] >> 20) == s1)
            cand[(size_t)b * PP + run + (unsigned)__popcll(mv[j] & lanemask)] = kv[j];
        run += (unsigned)__popcll(mv[j]);
    }
}

// ---------------- kernel 4: exact top-k among candidates + per-image + final ----------------
// grid BB x 1024; last-done block computes the 3 outputs.
__global__ __launch_bounds__(1024) void k_select(
    const unsigned* __restrict__ cand, const unsigned* __restrict__ cidx,
    const float* __restrict__ h1s, const int* __restrict__ seli,
    const float* __restrict__ pcp, const float* __restrict__ locp,
    int* __restrict__ resn, int* __restrict__ resk,
    float* __restrict__ resc, float* __restrict__ resl,
    unsigned* __restrict__ done, float* __restrict__ out)
{
    __shared__ unsigned ch[1024];
    __shared__ float cs[1024];
    __shared__ int lastflag;
    const int b = blockIdx.x, tid = threadIdx.x;
    const int sel1 = seli[b * 4 + 0], kk1 = seli[b * 4 + 1];
    const int np   = seli[b * 4 + 2], k   = seli[b * 4 + 3];
    const unsigned ncand = cidx[b];

    // neg-sum over buckets strictly above sel1, from per-chunk bin sums
    float nh = 0.f;
    for (int i = tid * 4; i < tid * 4 + 4; i++) {
        if (i > sel1) {
            for (int c = 0; c < NCHUNK; c++) nh += h1s[(b * NCHUNK + c) * 4096 + i];
        }
    }
    float negsum_high = block_sum_f(nh);

    // pass 1: hist on bits [19:10] of candidates
    ch[tid] = 0u; cs[tid] = 0.f;
    __syncthreads();
    for (unsigned i = tid; i < ncand; i += 1024) {
        unsigned v = cand[(size_t)b * PP + i];
        unsigned bin = (v >> 10) & 1023u;
        atomicAdd(&ch[bin], 1u);
        atomicAdd(&cs[bin], __uint_as_float(v));
    }
    __syncthreads();
    int sel2, kk2;
    find_kth_par<1024>(ch, (sel1 < 0) ? 0 : kk1, &sel2, &kk2);
    float sumhi2 = block_sum_f((sel2 >= 0 && tid > sel2) ? cs[tid] : 0.f);

    // pass 2: hist on bits [9:0] within sub-bucket sel2
    __syncthreads();
    ch[tid] = 0u; cs[tid] = 0.f;
    __syncthreads();
    if (sel2 >= 0) {
        for (unsigned i = tid; i < ncand; i += 1024) {
            unsigned v = cand[(size_t)b * PP + i];
            if (((v >> 10) & 1023u) == (unsigned)sel2) {
                atomicAdd(&ch[v & 1023u], 1u);
                atomicAdd(&cs[v & 1023u], __uint_as_float(v));
            }
        }
    }
    __syncthreads();
    int sel3, needeq;
    find_kth_par<1024>(ch, (sel2 < 0) ? 0 : kk2, &sel3, &needeq);
    float sumhi3 = block_sum_f((sel3 >= 0 && tid > sel3) ? cs[tid] : 0.f);

    if (tid == 0) {
        float pcsum = 0.f, locsum = 0.f;
        for (int c = 0; c < NCHUNK; c++) {
            pcsum += pcp[b * NCHUNK + c];
            locsum += locp[b * NCHUNK + c];
        }
        float add = 0.f;
        if (sel3 >= 0 && needeq > 0) {
            unsigned Kstar = ((unsigned)sel1 << 20) | ((unsigned)sel2 << 10) | (unsigned)sel3;
            add = needeq * __uint_as_float(Kstar);
        }
        resn[b] = np;
        resk[b] = k;
        resc[b] = pcsum + negsum_high + sumhi2 + sumhi3 + add;
        resl[b] = locsum;
        __threadfence();
        unsigned old = atomicAdd(done, 1u);
        lastflag = (old == BB - 1) ? 1 : 0;
    }
    __syncthreads();
    if (!lastflag || tid != 0) return;

    __threadfence();
    volatile int* vrn = (volatile int*)resn;
    volatile int* vrk = (volatile int*)resk;
    volatile float* vrc = (volatile float*)resc;
    volatile float* vrl = (volatile float*)resl;
    int npt = 0; long long maskc = 0; float clsnum = 0.f, locnum = 0.f;
    for (int b2 = 0; b2 < BB; b2++) {
        npt += vrn[b2];
        maskc += (long long)vrn[b2] + vrk[b2];
        clsnum += vrc[b2];
        locnum += vrl[b2];
    }
    float denom_loc = (float)((4 * npt > 1) ? 4 * npt : 1);
    float denom_cls = (float)((maskc > 1) ? maskc : 1);
    float loss_loc = locnum / denom_loc;
    float loss_cls = clsnum / denom_cls;
    out[0] = (loss_cls + loss_loc) / (float)npt;
    out[1] = loss_loc;
    out[2] = loss_cls;
}

extern "C" void kernel_launch(void* const* d_in, const int* in_sizes, int n_in,
                              void* d_out, int out_size, void* d_ws, size_t ws_size,
                              hipStream_t stream)
{
    const float* loc_preds = (const float*)d_in[0];
    const float* cls_preds = (const float*)d_in[1];
    const float* priorbox  = (const float*)d_in[2];
    const float* targets   = (const float*)d_in[3];
    float* out = (float*)d_out;

    char* ws = (char*)d_ws;
    unsigned long long* bestp = (unsigned long long*)(ws + OFF_BESTP);
    unsigned* h1c    = (unsigned*)(ws + OFF_H1C);
    float*    h1s    = (float*)(ws + OFF_H1S);
    int*      nposp  = (int*)(ws + OFF_NPOSP);
    float*    pcp    = (float*)(ws + OFF_PCP);
    float*    locp   = (float*)(ws + OFF_LOCP);
    unsigned* cidx   = (unsigned*)(ws + OFF_CIDX);
    unsigned* done   = (unsigned*)(ws + OFF_DONE);
    int*      seli   = (int*)(ws + OFF_SELI);
    int*      resn   = (int*)(ws + OFF_RESN);
    int*      resk   = (int*)(ws + OFF_RESK);
    float*    resc   = (float*)(ws + OFF_RESC);
    float*    resl   = (float*)(ws + OFF_RESL);
    unsigned* keys   = (unsigned*)(ws + OFF_KEYS);
    float*    bto    = (float*)(ws + OFF_BTO);
    unsigned char* bti = (unsigned char*)(ws + OFF_BTI);
    unsigned* cand   = (unsigned*)(ws + OFF_CAND);

    k_match<<<dim3(NCHUNK, BB), 1024, 0, stream>>>(priorbox, targets, bestp, bto, bti);
    k_loss<<<dim3(NCHUNK, BB), 1024, 0, stream>>>(loc_preds, cls_preds, priorbox, targets,
                                                  bestp, bto, bti, keys, h1c, h1s,
                                                  nposp, pcp, locp, cidx, done);
    k_compact<<<dim3(NCHUNK, BB), 1024, 0, stream>>>(keys, h1c, nposp, cand, cidx, seli);
    k_select<<<BB, 1024, 0, stream>>>(cand, cidx, h1s, seli, pcp, locp,
                                      resn, resk, resc, resl, done, out);
}